// Round 7
// baseline (298.988 us; speedup 1.0000x reference)
//
#include <hip/hip_runtime.h>
#include <hip/hip_bf16.h>
#include <cstddef>
#include <cstdint>

// ---------------------------------------------------------------------------
// Problem constants
// ---------------------------------------------------------------------------
#define B_   128
#define N_   8
#define C_   1024
#define FS_  14
#define POS_ 196            // 14*14
#define P_   20
#define HWC_ 9              // 3*3 cells
#define CMID_ 256
#define FEATD_ 2304         // CMID*HWC
#define H1_  1024
#define O_   27
#define PROWS_ (B_*N_*HWC_) // 9216 pooled rows (bn,cell)

typedef __attribute__((ext_vector_type(8))) short bf16x8;   // 8 bf16 (4 VGPRs)
typedef __attribute__((ext_vector_type(4))) float f32x4;

// async global->LDS, 16B per lane; LDS dest = wave-uniform base + lane*16
__device__ __forceinline__ void gld16(const void* g, void* l) {
    __builtin_amdgcn_global_load_lds(
        (const __attribute__((address_space(1))) unsigned int*)g,
        (__attribute__((address_space(3))) unsigned int*)l, 16, 0, 0);
}

// ---------------------------------------------------------------------------
// Kernel 1a: split-K partials of Wc = w2 @ w1
// ---------------------------------------------------------------------------
__global__ __launch_bounds__(256) void wcombine_split_kernel(
    const float* __restrict__ w1,   // (512,1024)
    const float* __restrict__ w2,   // (256,512)
    float* __restrict__ wpart)      // (8,256,1024) fp32
{
    const int tid = threadIdx.x;
    const int tx = tid & 15, ty = tid >> 4;
    const int c0 = blockIdx.x * 64;
    const int o0 = blockIdx.y * 64;
    const int kb = blockIdx.z * 64;
    __shared__ __align__(16) float As[16][68];
    __shared__ __align__(16) float Bs[16][68];
    float acc[4][4] = {};
    for (int k0 = kb; k0 < kb + 64; k0 += 16) {
        for (int i = tid; i < 64 * 16; i += 256) {
            int k = i & 15, m = i >> 4;
            As[k][m] = w2[(size_t)(o0 + m) * 512 + k0 + k];
        }
        for (int i = tid; i < 64 * 16; i += 256) {
            int n = i & 63, k = i >> 6;
            Bs[k][n] = w1[(size_t)(k0 + k) * 1024 + c0 + n];
        }
        __syncthreads();
        #pragma unroll
        for (int k = 0; k < 16; ++k) {
            float4 a = *(const float4*)&As[k][ty * 4];
            float4 b = *(const float4*)&Bs[k][tx * 4];
            float av[4] = {a.x, a.y, a.z, a.w};
            float bv[4] = {b.x, b.y, b.z, b.w};
            #pragma unroll
            for (int i = 0; i < 4; ++i)
                #pragma unroll
                for (int j = 0; j < 4; ++j)
                    acc[i][j] += av[i] * bv[j];
        }
        __syncthreads();
    }
    float* dst = wpart + (size_t)blockIdx.z * (256 * 1024);
    for (int i = 0; i < 4; ++i) {
        float4 v = make_float4(acc[i][0], acc[i][1], acc[i][2], acc[i][3]);
        *(float4*)&dst[(size_t)(o0 + ty * 4 + i) * 1024 + c0 + tx * 4] = v;
    }
}

// ---------------------------------------------------------------------------
// Kernel 1b: Wc = bf16( sum_z wpart[z] )
// ---------------------------------------------------------------------------
__global__ __launch_bounds__(256) void wc_reduce_kernel(
    const float* __restrict__ wpart, __hip_bfloat16* __restrict__ Wc)
{
    int idx = blockIdx.x * 256 + threadIdx.x;
    float s = 0.f;
    #pragma unroll
    for (int z = 0; z < 8; ++z) s += wpart[(size_t)z * (256 * 1024) + idx];
    Wc[idx] = __float2bfloat16(s);
}

// ---------------------------------------------------------------------------
// Kernel 2: roipool — ROI-align on raw fmap with a PER-BLOCK LDS tap table.
//   History: R4 inline math 60 µs (VALU-issue-bound: ~1440 VALU/thread of
//   replicated coord math); R5 GLOBAL table 89 µs (serial s_load misses);
//   R6 6-blocks/CU 55-59 µs (TLP can't remove issued instructions).
//   Fix: build all 288 samples' {packed pos/dx/dy, 4 folded weights} in LDS
//   once per block (~50 VALU, overlaps staging), then the per-tap work is
//   2 broadcast LDS reads + 4 data LDS reads + 4 fmaf + ~6 int ops.
//   LDS: 25.2 KB data (stride 197 -> 2-way free) + 5.8 KB taps = 31 KB
//   -> 5 blocks/CU. Weight products and fmaf order identical to R5's
//   (passed, same absmax).
// ---------------------------------------------------------------------------
#define CCH_   32
#define LSTR_  197
#define NSAMP_ 288   // 8 boxes * 9 cells * 4 taps
__global__ __launch_bounds__(256, 5) void roipool_kernel(
    const float* __restrict__ fmap,          // (128,1024,196)
    const float* __restrict__ boxes,         // (128,8,4)
    __hip_bfloat16* __restrict__ pooled)     // (9216, 1024)
{
    const int b  = blockIdx.y;
    const int c0 = blockIdx.x * CCH_;
    const int tid = threadIdx.x;
    __shared__ float Ls[CCH_ * LSTR_];                 // 25.2 KB
    __shared__ int   Tpos[NSAMP_];                     // packed pos|dx|dy
    __shared__ __align__(16) float Tw[NSAMP_ * 4];     // folded weights

    // ---- stage fmap chunk: 32 c-rows x 49 float4 (= 196 pos) ----
    const float* src = fmap + ((size_t)b * C_ + c0) * POS_;
    for (int i = tid; i < CCH_ * 49; i += 256) {
        int c = i / 49, ch = i - c * 49;
        float4 v = *(const float4*)(src + (size_t)c * POS_ + ch * 4);
        float* dst = &Ls[c * LSTR_ + ch * 4];
        dst[0] = v.x; dst[1] = v.y; dst[2] = v.z; dst[3] = v.w;
    }

    // ---- build tap table: 288 samples (8 boxes x 9 cells x 4 taps) ----
    for (int s = tid; s < NSAMP_; s += 256) {
        int n = s / 36, rem = s - n * 36;
        int cell = rem >> 2, tap = rem & 3;
        int chh = cell / 3, cww = cell % 3;
        int si = tap >> 1, sj = tap & 1;
        const float* bx = boxes + ((size_t)b * N_ + n) * 4;
        float x1 = bx[0], y1 = bx[1], x2 = bx[2], y2 = bx[3];
        float bw = (x2 - x1) * (1.0f / 3.0f);
        float bh = (y2 - y1) * (1.0f / 3.0f);
        float yy = y1 + ((float)(2 * chh + si) + 0.5f) * 0.5f * bh;
        float xx = x1 + ((float)(2 * cww + sj) + 0.5f) * 0.5f * bw;
        bool valid = (yy > -1.0f) && (yy < (float)FS_) &&
                     (xx > -1.0f) && (xx < (float)FS_);
        float y = fminf(fmaxf(yy, 0.0f), (float)(FS_ - 1));
        float x = fminf(fmaxf(xx, 0.0f), (float)(FS_ - 1));
        int y0 = (int)floorf(y);
        int x0 = (int)floorf(x);
        int y1i = min(y0 + 1, FS_ - 1);
        int x1i = min(x0 + 1, FS_ - 1);
        float ly = y - (float)y0, lx = x - (float)x0;
        float hy = 1.0f - ly,     hx = 1.0f - lx;
        float q = valid ? 0.25f : 0.0f;
        int p00 = (y0 * FS_ + x0) * 4;          // byte offset, <= 780
        int dxb = (x1i - x0) * 4;               // 0 or 4
        int dyb = (y1i - y0) * (FS_ * 4);       // 0 or 56
        Tpos[s] = p00 | (dxb << 12) | (dyb << 16);
        Tw[s * 4 + 0] = hy * hx * q;
        Tw[s * 4 + 1] = hy * lx * q;
        Tw[s * 4 + 2] = ly * hx * q;
        Tw[s * 4 + 3] = ly * lx * q;
    }
    __syncthreads();

    // ---- pool: lane = channel (tid&31), box = tid>>5 ----
    const int cl = tid & 31;
    const int n  = tid >> 5;
    const char* lsb = (const char*)&Ls[cl * LSTR_];
    __hip_bfloat16* prow = pooled + (size_t)((b * N_ + n) * HWC_) * C_ + c0 + cl;

    #pragma unroll
    for (int cell = 0; cell < 9; ++cell) {
        float acc = 0.0f;
        const int sbase = n * 36 + cell * 4;
        #pragma unroll
        for (int tap = 0; tap < 4; ++tap) {
            int pk = Tpos[sbase + tap];                      // broadcast
            float4 w = *(const float4*)&Tw[(sbase + tap) * 4];  // broadcast
            int p00 = pk & 0xFFF;
            int dxb = (pk >> 12) & 0xF;
            int dyb = pk >> 16;
            float v00 = *(const float*)(lsb + p00);
            float v01 = *(const float*)(lsb + p00 + dxb);
            float v10 = *(const float*)(lsb + p00 + dyb);
            float v11 = *(const float*)(lsb + p00 + dyb + dxb);
            acc = fmaf(w.x, v00, acc);
            acc = fmaf(w.y, v01, acc);
            acc = fmaf(w.z, v10, acc);
            acc = fmaf(w.w, v11, acc);
        }
        prow[(size_t)cell * C_] = __float2bfloat16(acc);
    }
}

// ---------------------------------------------------------------------------
// Kernel 3: pooledgemm — feat = pooled @ Wc^T, fp32 out.
//   M=9216, N=256, K=1024; both operands K-contiguous bf16, gld16 staging.
// ---------------------------------------------------------------------------
__global__ __launch_bounds__(256, 4) void pooledgemm_kernel(
    const __hip_bfloat16* __restrict__ A,    // pooled (9216 x 1024)
    const __hip_bfloat16* __restrict__ Bm,   // Wc (256 x 1024)
    float* __restrict__ Cout)                // feat (9216 x 256) fp32
{
    const int tid = threadIdx.x;
    const int wave = tid >> 6, lane = tid & 63;
    const int r0 = blockIdx.y * 64, n0 = blockIdx.x * 64;
    const int wm = (wave >> 1) * 32, wn = (wave & 1) * 32;
    const int m16 = lane & 15, quad = lane >> 4;
    const int K = C_;
    __shared__ __align__(16) __hip_bfloat16 As[64 * 64];
    __shared__ __align__(16) __hip_bfloat16 Bs[64 * 64];

    f32x4 acc[2][2];
    #pragma unroll
    for (int i = 0; i < 2; ++i)
        #pragma unroll
        for (int j = 0; j < 2; ++j)
            acc[i][j] = (f32x4){0.f, 0.f, 0.f, 0.f};

    const int qa = wave * 64 + lane;                 // 0..255
    const int ms0 = qa >> 3, cs0 = (qa & 7) ^ (ms0 & 7);
    const int qb1 = qa + 256;
    const int ms1 = qb1 >> 3, cs1 = (qb1 & 7) ^ (ms1 & 7);
    const size_t rA0 = (size_t)(r0 + ms0) * K + cs0 * 8;
    const size_t rA1 = (size_t)(r0 + ms1) * K + cs1 * 8;
    const size_t rB0 = (size_t)(n0 + ms0) * K + cs0 * 8;
    const size_t rB1 = (size_t)(n0 + ms1) * K + cs1 * 8;

    for (int k0 = 0; k0 < K; k0 += 64) {
        gld16(A  + rA0 + k0, &As[wave * 512]);
        gld16(Bm + rB0 + k0, &Bs[wave * 512]);
        gld16(A  + rA1 + k0, &As[2048 + wave * 512]);
        gld16(Bm + rB1 + k0, &Bs[2048 + wave * 512]);
        __syncthreads();
        #pragma unroll
        for (int ks = 0; ks < 2; ++ks) {
            bf16x8 af[2], bfv[2];
            #pragma unroll
            for (int t = 0; t < 2; ++t) {
                int m = wm + t * 16 + m16;
                int cp = (ks * 4 + quad) ^ (m & 7);
                af[t] = *(const bf16x8*)&As[(m * 8 + cp) * 8];
                int n = wn + t * 16 + m16;
                int cq = (ks * 4 + quad) ^ (n & 7);
                bfv[t] = *(const bf16x8*)&Bs[(n * 8 + cq) * 8];
            }
            #pragma unroll
            for (int i = 0; i < 2; ++i)
                #pragma unroll
                for (int j = 0; j < 2; ++j)
                    acc[i][j] = __builtin_amdgcn_mfma_f32_16x16x32_bf16(
                        af[i], bfv[j], acc[i][j], 0, 0, 0);
        }
        __syncthreads();
    }

    #pragma unroll
    for (int i = 0; i < 2; ++i) {
        #pragma unroll
        for (int j = 0; j < 2; ++j) {
            int col = n0 + wn + j * 16 + m16;
            int rbase = r0 + wm + i * 16 + quad * 4;
            #pragma unroll
            for (int g = 0; g < 4; ++g)
                Cout[(size_t)(rbase + g) * 256 + col] = acc[i][j][g];
        }
    }
}

// ---------------------------------------------------------------------------
// MFMA GEMM (fc1): h1 = relu(diff @ fc1_wp^T + b). 32x64 tile, BK=64.
// ---------------------------------------------------------------------------
__global__ __launch_bounds__(256, 4) void fc1_gemm_kernel(
    const __hip_bfloat16* __restrict__ A,    // diff (1024 x 2304)
    const __hip_bfloat16* __restrict__ Bm,   // fc1_wp (1024 x 2304)
    const float* __restrict__ bias,
    float* __restrict__ C)                   // h1 (1024 x 1024)
{
    const int tid = threadIdx.x;
    const int wave = tid >> 6, lane = tid & 63;
    const int r0 = blockIdx.y * 32, n0 = blockIdx.x * 64;
    const int wm = (wave >> 1) * 16, wn = (wave & 1) * 32;
    const int m16 = lane & 15, quad = lane >> 4;
    const int K = FEATD_;
    __shared__ __align__(16) __hip_bfloat16 As[32 * 64];
    __shared__ __align__(16) __hip_bfloat16 Bs[64 * 64];

    f32x4 acc[2];
    acc[0] = (f32x4){0.f, 0.f, 0.f, 0.f};
    acc[1] = (f32x4){0.f, 0.f, 0.f, 0.f};

    const int qa = wave * 64 + lane;                 // 0..255
    const int msA = qa >> 3, csA = (qa & 7) ^ (msA & 7);
    const int qb1 = qa + 256;
    const int msB1 = qb1 >> 3, csB1 = (qb1 & 7) ^ (msB1 & 7);
    const size_t rA  = (size_t)(r0 + msA)  * K + csA  * 8;
    const size_t rB0 = (size_t)(n0 + msA)  * K + csA  * 8;
    const size_t rB1 = (size_t)(n0 + msB1) * K + csB1 * 8;

    for (int k0 = 0; k0 < K; k0 += 64) {
        gld16(A  + rA  + k0, &As[wave * 512]);
        gld16(Bm + rB0 + k0, &Bs[wave * 512]);
        gld16(Bm + rB1 + k0, &Bs[2048 + wave * 512]);
        __syncthreads();
        #pragma unroll
        for (int ks = 0; ks < 2; ++ks) {
            bf16x8 af, bfv[2];
            int m = wm + m16;
            int cp = (ks * 4 + quad) ^ (m & 7);
            af = *(const bf16x8*)&As[(m * 8 + cp) * 8];
            #pragma unroll
            for (int t = 0; t < 2; ++t) {
                int n = wn + t * 16 + m16;
                int cq = (ks * 4 + quad) ^ (n & 7);
                bfv[t] = *(const bf16x8*)&Bs[(n * 8 + cq) * 8];
            }
            #pragma unroll
            for (int j = 0; j < 2; ++j)
                acc[j] = __builtin_amdgcn_mfma_f32_16x16x32_bf16(
                    af, bfv[j], acc[j], 0, 0, 0);
        }
        __syncthreads();
    }

    #pragma unroll
    for (int j = 0; j < 2; ++j) {
        int col = n0 + wn + j * 16 + m16;
        int rbase = r0 + wm + quad * 4;
        float bv = bias[col];
        #pragma unroll
        for (int g = 0; g < 4; ++g) {
            int r = rbase + g;
            float v = acc[j][g] + bv;
            C[(size_t)r * H1_ + col] = v > 0.f ? v : 0.f;
        }
    }
}

// ---------------------------------------------------------------------------
// fc1_w (1024 x 2304 fp32, k = o*9+hw) -> bf16 permuted (k' = hw*256+o)
// ---------------------------------------------------------------------------
__global__ __launch_bounds__(256) void fc1w_perm_kernel(
    const float* __restrict__ src, __hip_bfloat16* __restrict__ dst)
{
    int h = blockIdx.x;
    int tid = threadIdx.x;
    __shared__ float buf[FEATD_];
    const float* s = src + (size_t)h * FEATD_;
    #pragma unroll
    for (int it = 0; it < 9; ++it)
        buf[it * 256 + tid] = s[it * 256 + tid];
    __syncthreads();
    __hip_bfloat16* d = dst + (size_t)h * FEATD_;
    #pragma unroll
    for (int it = 0; it < 9; ++it) {
        int dd = it * 256 + tid;       // hw = it, o = tid
        d[dd] = __float2bfloat16(buf[tid * HWC_ + it]);
    }
}

// ---------------------------------------------------------------------------
// inv[b][p] = n with pids[b][n]==p else -1
// ---------------------------------------------------------------------------
__global__ __launch_bounds__(64) void invmap_kernel(
    const int* __restrict__ pids, int* __restrict__ inv)
{
    int b = blockIdx.x;
    int p = threadIdx.x;
    if (p < P_) {
        int v = -1;
        for (int n = 0; n < N_; ++n)
            if (pids[b * N_ + n] == p) v = n;
        inv[b * P_ + p] = v;
    }
}

// ---------------------------------------------------------------------------
// meandiff (FUSED meanb+diff): for p = blockIdx.x, d = blockIdx.y*256+tid:
//   mean = (1/128) sum_b feat[b, inv[b][p], d]   (registers, never stored)
//   then for each b with n=inv[b][p] >= 0:
//     diff[(b*8+n)][d] = bf16(mean - feat[(b*8+n)][d])   (feat re-read, L2-hot)
//   Saves one full feat HBM pass + the mean_b round-trip + a launch.
//   Numerics identical to the split version (same accumulation order).
// ---------------------------------------------------------------------------
__global__ __launch_bounds__(256) void meandiff_kernel(
    const float* __restrict__ feat, const int* __restrict__ inv,
    __hip_bfloat16* __restrict__ diff)
{
    int p = blockIdx.x;
    int d = blockIdx.y * 256 + threadIdx.x;
    float acc = 0.0f;
    #pragma unroll 4
    for (int b = 0; b < B_; ++b) {
        int n = inv[b * P_ + p];
        if (n >= 0) acc += feat[(size_t)(b * N_ + n) * FEATD_ + d];
    }
    float mean = acc * (1.0f / (float)B_);
    #pragma unroll 4
    for (int b = 0; b < B_; ++b) {
        int n = inv[b * P_ + p];
        if (n >= 0) {
            size_t r = (size_t)(b * N_ + n);
            diff[r * FEATD_ + d] = __float2bfloat16(mean - feat[r * FEATD_ + d]);
        }
    }
}

// ---------------------------------------------------------------------------
// fc2: out[bn][o] = h1[bn] . fc2_w[o] + fc2_b[o]
// ---------------------------------------------------------------------------
__global__ __launch_bounds__(256) void fc2_kernel(
    const float* __restrict__ h1, const float* __restrict__ fc2_w,
    const float* __restrict__ fc2_b, float* __restrict__ out)
{
    int bn = blockIdx.x;
    int tid = threadIdx.x;
    __shared__ __align__(16) float row[H1_];
    __shared__ float partial[32][8];
    ((float4*)row)[tid] = ((const float4*)(h1 + (size_t)bn * H1_))[tid];
    __syncthreads();
    int o = tid >> 3, part = tid & 7;
    float acc = 0.0f;
    if (o < O_) {
        const float* wrow = fc2_w + (size_t)o * H1_ + part * 128;
        const float* hrow = row + part * 128;
        #pragma unroll 4
        for (int j = 0; j < 128; ++j) acc += hrow[j] * wrow[j];
    }
    partial[o][part] = acc;
    __syncthreads();
    if (part == 0 && o < O_) {
        float s = fc2_b[o];
        #pragma unroll
        for (int p = 0; p < 8; ++p) s += partial[o][p];
        out[(size_t)bn * O_ + o] = s;
    }
}

// ---------------------------------------------------------------------------
// Launch
// ---------------------------------------------------------------------------
extern "C" void kernel_launch(void* const* d_in, const int* in_sizes, int n_in,
                              void* d_out, int out_size, void* d_ws, size_t ws_size,
                              hipStream_t stream) {
    const float* fmap  = (const float*)d_in[0];
    const float* boxes = (const float*)d_in[1];
    const int*   pids  = (const int*)  d_in[2];
    const float* w1    = (const float*)d_in[3];
    const float* w2    = (const float*)d_in[4];
    const float* fc1_w = (const float*)d_in[5];
    const float* fc1_b = (const float*)d_in[6];
    const float* fc2_w = (const float*)d_in[7];
    const float* fc2_b = (const float*)d_in[8];
    float* out = (float*)d_out;

    // workspace layout (all 16B aligned; mean_b slot retained but unused)
    char* wsb = (char*)d_ws;
    __hip_bfloat16* Wc     = (__hip_bfloat16*)wsb;                      // 256*1024
    __hip_bfloat16* pooled = Wc + 256 * 1024;                           // 9216*1024
    __hip_bfloat16* fc1wp  = pooled + (size_t)PROWS_ * C_;              // 1024*2304
    __hip_bfloat16* diffp  = fc1wp + (size_t)H1_ * FEATD_;              // 1024*2304
    float* feat   = (float*)(diffp + (size_t)H1_ * FEATD_);             // 1024*2304
    float* mean_b = feat + (size_t)(B_ * N_) * FEATD_;                  // 20*2304 (unused)
    float* h1     = mean_b + (size_t)P_ * FEATD_;                       // 1024*1024
    int*   inv    = (int*)(h1 + (size_t)(B_ * N_) * H1_);               // 128*20
    float* wpart  = (float*)(inv + 128 * P_ + 64);                      // 8*256*1024

    hipLaunchKernelGGL(wcombine_split_kernel, dim3(16, 4, 8), dim3(256), 0, stream,
                       w1, w2, wpart);
    hipLaunchKernelGGL(wc_reduce_kernel, dim3(1024), dim3(256), 0, stream,
                       wpart, Wc);
    hipLaunchKernelGGL(roipool_kernel, dim3(C_ / CCH_, 128), dim3(256), 0, stream,
                       fmap, boxes, pooled);
    hipLaunchKernelGGL(pooledgemm_kernel, dim3(4, 144), dim3(256), 0, stream,
                       pooled, Wc, feat);
    hipLaunchKernelGGL(fc1w_perm_kernel, dim3(1024), dim3(256), 0, stream,
                       fc1_w, fc1wp);
    hipLaunchKernelGGL(invmap_kernel, dim3(128), dim3(64), 0, stream,
                       pids, inv);
    hipLaunchKernelGGL(meandiff_kernel, dim3(20, 9), dim3(256), 0, stream,
                       feat, inv, diffp);
    hipLaunchKernelGGL(fc1_gemm_kernel, dim3(16, 32), dim3(256), 0, stream,
                       diffp, fc1wp, fc1_b, h1);
    hipLaunchKernelGGL(fc2_kernel, dim3(1024), dim3(256), 0, stream,
                       h1, fc2_w, fc2_b, out);
}

// Round 8
// 296.437 us; speedup vs baseline: 1.0086x; 1.0086x over previous
//
#include <hip/hip_runtime.h>
#include <hip/hip_bf16.h>
#include <cstddef>
#include <cstdint>

// ---------------------------------------------------------------------------
// Problem constants
// ---------------------------------------------------------------------------
#define B_   128
#define N_   8
#define C_   1024
#define FS_  14
#define POS_ 196            // 14*14
#define P_   20
#define HWC_ 9              // 3*3 cells
#define CMID_ 256
#define FEATD_ 2304         // CMID*HWC
#define H1_  1024
#define O_   27
#define PROWS_ (B_*N_*HWC_) // 9216 pooled rows (bn,cell)

typedef __attribute__((ext_vector_type(8))) short bf16x8;   // 8 bf16 (4 VGPRs)
typedef __attribute__((ext_vector_type(4))) float f32x4;

// async global->LDS, 16B per lane; LDS dest = wave-uniform base + lane*16
__device__ __forceinline__ void gld16(const void* g, void* l) {
    __builtin_amdgcn_global_load_lds(
        (const __attribute__((address_space(1))) unsigned int*)g,
        (__attribute__((address_space(3))) unsigned int*)l, 16, 0, 0);
}

// ---------------------------------------------------------------------------
// Kernel 1a: split-K partials of Wc = w2 @ w1
// ---------------------------------------------------------------------------
__global__ __launch_bounds__(256) void wcombine_split_kernel(
    const float* __restrict__ w1,   // (512,1024)
    const float* __restrict__ w2,   // (256,512)
    float* __restrict__ wpart)      // (8,256,1024) fp32
{
    const int tid = threadIdx.x;
    const int tx = tid & 15, ty = tid >> 4;
    const int c0 = blockIdx.x * 64;
    const int o0 = blockIdx.y * 64;
    const int kb = blockIdx.z * 64;
    __shared__ __align__(16) float As[16][68];
    __shared__ __align__(16) float Bs[16][68];
    float acc[4][4] = {};
    for (int k0 = kb; k0 < kb + 64; k0 += 16) {
        for (int i = tid; i < 64 * 16; i += 256) {
            int k = i & 15, m = i >> 4;
            As[k][m] = w2[(size_t)(o0 + m) * 512 + k0 + k];
        }
        for (int i = tid; i < 64 * 16; i += 256) {
            int n = i & 63, k = i >> 6;
            Bs[k][n] = w1[(size_t)(k0 + k) * 1024 + c0 + n];
        }
        __syncthreads();
        #pragma unroll
        for (int k = 0; k < 16; ++k) {
            float4 a = *(const float4*)&As[k][ty * 4];
            float4 b = *(const float4*)&Bs[k][tx * 4];
            float av[4] = {a.x, a.y, a.z, a.w};
            float bv[4] = {b.x, b.y, b.z, b.w};
            #pragma unroll
            for (int i = 0; i < 4; ++i)
                #pragma unroll
                for (int j = 0; j < 4; ++j)
                    acc[i][j] += av[i] * bv[j];
        }
        __syncthreads();
    }
    float* dst = wpart + (size_t)blockIdx.z * (256 * 1024);
    for (int i = 0; i < 4; ++i) {
        float4 v = make_float4(acc[i][0], acc[i][1], acc[i][2], acc[i][3]);
        *(float4*)&dst[(size_t)(o0 + ty * 4 + i) * 1024 + c0 + tx * 4] = v;
    }
}

// ---------------------------------------------------------------------------
// Kernel 1b: Wc = bf16( sum_z wpart[z] )
// ---------------------------------------------------------------------------
__global__ __launch_bounds__(256) void wc_reduce_kernel(
    const float* __restrict__ wpart, __hip_bfloat16* __restrict__ Wc)
{
    int idx = blockIdx.x * 256 + threadIdx.x;
    float s = 0.f;
    #pragma unroll
    for (int z = 0; z < 8; ++z) s += wpart[(size_t)z * (256 * 1024) + idx];
    Wc[idx] = __float2bfloat16(s);
}

// ---------------------------------------------------------------------------
// Kernel 2: roipool via MFMA.  pooled[b] (72x1024) = W_pool[b] (72x196) @
//   fmap[b]^T — both operands K(pos)-contiguous, so no transpose problem.
//   R4-R7 post-mortem: every scalar-gather variant floored at 55-63 µs
//   because the per-tap LDS gather issues ~216 ds_read/thread (~33 µs of
//   LDS-pipe issue alone). This version replaces the gather with 35
//   MFMA fragment reads/thread and ONE single-shot staging phase per block.
//   Per (batch, 64-channel chunk) block:
//     phase 0: fmap chunk fp32->bf16 into Bs[64][232] (fmap read once,
//              coalesced); zero As[72][232]; zero Bs k-pad.
//     phase 1: 72 threads scatter-accumulate their row's 16 tap weights
//              (race-free: one thread per output row; coord math identical
//              to R6/R7).
//     phase 2: 5x1x7 MFMAs per wave (wave = 16-channel column group).
//   Stride 232 bf16 (= 29x16B): fragment reads 2-way bank-aliased = free.
//   LDS 63.1 KB -> 2 blocks/CU. K padded 196->224 with zeros both sides.
//   NOTE: tap weights now quantize to bf16 (MFMA input) — absmax may rise
//   one bf16 ulp class (0.0039 -> <=0.0078).
// ---------------------------------------------------------------------------
#define CCH_   64
#define SSTR_  232           // row stride in bf16 (29*8, 16B-aligned rows)
#define AROWS_ 72
#define AOFF_  (AROWS_ * SSTR_)   // Bs base offset in elems
struct bf4s { __hip_bfloat162 lo, hi; };
__global__ __launch_bounds__(256, 2) void roipool_kernel(
    const float* __restrict__ fmap,          // (128,1024,196)
    const float* __restrict__ boxes,         // (128,8,4)
    __hip_bfloat16* __restrict__ pooled)     // (9216, 1024)
{
    const int b  = blockIdx.y;
    const int c0 = blockIdx.x * CCH_;
    const int tid = threadIdx.x;
    __shared__ __align__(16) __hip_bfloat16 Ls[(AROWS_ + CCH_) * SSTR_];

    // ---- phase 0a: issue fmap chunk loads (64 rows x 49 float4) ----
    float4 vbuf[13];
    const float* src = fmap + ((size_t)b * C_ + c0) * POS_;
    #pragma unroll
    for (int it = 0; it < 13; ++it) {
        int i = tid + it * 256;
        if (i < CCH_ * 49) {
            int c = i / 49, ch = i - c * 49;
            vbuf[it] = *(const float4*)(src + (size_t)c * POS_ + ch * 4);
        }
    }
    // ---- phase 0b: zero A tile (72x232 bf16 = 2088 x 16B) ----
    {
        const uint4 z = {0, 0, 0, 0};
        #pragma unroll
        for (int it = 0; it < 9; ++it) {
            int i = tid + it * 256;
            if (i < 2088) *(uint4*)((char*)Ls + i * 16) = z;
        }
    }
    // ---- phase 0c: convert + write fmap chunk to Bs ----
    #pragma unroll
    for (int it = 0; it < 13; ++it) {
        int i = tid + it * 256;
        if (i < CCH_ * 49) {
            int c = i / 49, ch = i - c * 49;
            float4 v = vbuf[it];
            bf4s t;
            t.lo.x = __float2bfloat16(v.x); t.lo.y = __float2bfloat16(v.y);
            t.hi.x = __float2bfloat16(v.z); t.hi.y = __float2bfloat16(v.w);
            *(bf4s*)&Ls[AOFF_ + c * SSTR_ + ch * 4] = t;
        }
    }
    // ---- phase 0d: zero Bs k-pad (64 rows x elems 196..231 = 1152 dw) ----
    {
        #pragma unroll
        for (int it = 0; it < 5; ++it) {
            int i = tid + it * 256;
            if (i < CCH_ * 18) {
                int r = i / 18, kd = i - r * 18;
                *(unsigned int*)&Ls[AOFF_ + r * SSTR_ + 196 + kd * 2] = 0;
            }
        }
    }
    __syncthreads();

    // ---- phase 1: scatter tap weights (one thread per output row) ----
    if (tid < AROWS_) {
        const int m = tid;
        const int n = m / 9, cell = m - n * 9;
        const int chh = cell / 3, cww = cell % 3;
        float4 bx = *(const float4*)(boxes + ((size_t)b * N_ + n) * 4);
        float x1 = bx.x, y1 = bx.y, x2 = bx.z, y2 = bx.w;
        float bw = (x2 - x1) * (1.0f / 3.0f);
        float bh = (y2 - y1) * (1.0f / 3.0f);
        __hip_bfloat16* row = &Ls[m * SSTR_];
        #pragma unroll
        for (int si = 0; si < 2; ++si) {
            float yy = y1 + ((float)(2 * chh + si) + 0.5f) * 0.5f * bh;
            #pragma unroll
            for (int sj = 0; sj < 2; ++sj) {
                float xx = x1 + ((float)(2 * cww + sj) + 0.5f) * 0.5f * bw;
                bool valid = (yy > -1.0f) && (yy < (float)FS_) &&
                             (xx > -1.0f) && (xx < (float)FS_);
                float y = fminf(fmaxf(yy, 0.0f), (float)(FS_ - 1));
                float x = fminf(fmaxf(xx, 0.0f), (float)(FS_ - 1));
                int y0 = (int)floorf(y);
                int x0 = (int)floorf(x);
                int y1i = min(y0 + 1, FS_ - 1);
                int x1i = min(x0 + 1, FS_ - 1);
                float ly = y - (float)y0, lx = x - (float)x0;
                float hy = 1.0f - ly,     hx = 1.0f - lx;
                float q = valid ? 0.25f : 0.0f;
                int p00 = y0 * FS_ + x0, p01 = y0 * FS_ + x1i;
                int p10 = y1i * FS_ + x0, p11 = y1i * FS_ + x1i;
                row[p00] = __float2bfloat16(__bfloat162float(row[p00]) + hy * hx * q);
                row[p01] = __float2bfloat16(__bfloat162float(row[p01]) + hy * lx * q);
                row[p10] = __float2bfloat16(__bfloat162float(row[p10]) + ly * hx * q);
                row[p11] = __float2bfloat16(__bfloat162float(row[p11]) + ly * lx * q);
            }
        }
    }
    __syncthreads();

    // ---- phase 2: MFMA — each wave owns 16 channels (cols) ----
    const int wave = tid >> 6, lane = tid & 63;
    const int m16 = lane & 15, quad = lane >> 4;
    f32x4 acc[5];
    #pragma unroll
    for (int mt = 0; mt < 5; ++mt) acc[mt] = (f32x4){0.f, 0.f, 0.f, 0.f};

    const int nrow = wave * 16 + m16;   // channel row in Bs
    #pragma unroll
    for (int kk = 0; kk < 7; ++kk) {
        bf16x8 bfv = *(const bf16x8*)&Ls[AOFF_ + nrow * SSTR_ + kk * 32 + quad * 8];
        #pragma unroll
        for (int mt = 0; mt < 5; ++mt) {
            bf16x8 af = *(const bf16x8*)&Ls[(mt * 16 + m16) * SSTR_ + kk * 32 + quad * 8];
            acc[mt] = __builtin_amdgcn_mfma_f32_16x16x32_bf16(af, bfv, acc[mt], 0, 0, 0);
        }
    }

    // ---- epilogue: rows = mt*16 + quad*4 + g (< 72), col = channel ----
    const int col = c0 + wave * 16 + m16;
    #pragma unroll
    for (int mt = 0; mt < 5; ++mt) {
        #pragma unroll
        for (int g = 0; g < 4; ++g) {
            int row = mt * 16 + quad * 4 + g;
            if (row < AROWS_)
                pooled[(size_t)(b * AROWS_ + row) * C_ + col] =
                    __float2bfloat16(acc[mt][g]);
        }
    }
}

// ---------------------------------------------------------------------------
// Kernel 3: pooledgemm — feat = pooled @ Wc^T, fp32 out.
//   M=9216, N=256, K=1024; both operands K-contiguous bf16, gld16 staging.
// ---------------------------------------------------------------------------
__global__ __launch_bounds__(256, 4) void pooledgemm_kernel(
    const __hip_bfloat16* __restrict__ A,    // pooled (9216 x 1024)
    const __hip_bfloat16* __restrict__ Bm,   // Wc (256 x 1024)
    float* __restrict__ Cout)                // feat (9216 x 256) fp32
{
    const int tid = threadIdx.x;
    const int wave = tid >> 6, lane = tid & 63;
    const int r0 = blockIdx.y * 64, n0 = blockIdx.x * 64;
    const int wm = (wave >> 1) * 32, wn = (wave & 1) * 32;
    const int m16 = lane & 15, quad = lane >> 4;
    const int K = C_;
    __shared__ __align__(16) __hip_bfloat16 As[64 * 64];
    __shared__ __align__(16) __hip_bfloat16 Bs[64 * 64];

    f32x4 acc[2][2];
    #pragma unroll
    for (int i = 0; i < 2; ++i)
        #pragma unroll
        for (int j = 0; j < 2; ++j)
            acc[i][j] = (f32x4){0.f, 0.f, 0.f, 0.f};

    const int qa = wave * 64 + lane;                 // 0..255
    const int ms0 = qa >> 3, cs0 = (qa & 7) ^ (ms0 & 7);
    const int qb1 = qa + 256;
    const int ms1 = qb1 >> 3, cs1 = (qb1 & 7) ^ (ms1 & 7);
    const size_t rA0 = (size_t)(r0 + ms0) * K + cs0 * 8;
    const size_t rA1 = (size_t)(r0 + ms1) * K + cs1 * 8;
    const size_t rB0 = (size_t)(n0 + ms0) * K + cs0 * 8;
    const size_t rB1 = (size_t)(n0 + ms1) * K + cs1 * 8;

    for (int k0 = 0; k0 < K; k0 += 64) {
        gld16(A  + rA0 + k0, &As[wave * 512]);
        gld16(Bm + rB0 + k0, &Bs[wave * 512]);
        gld16(A  + rA1 + k0, &As[2048 + wave * 512]);
        gld16(Bm + rB1 + k0, &Bs[2048 + wave * 512]);
        __syncthreads();
        #pragma unroll
        for (int ks = 0; ks < 2; ++ks) {
            bf16x8 af[2], bfv[2];
            #pragma unroll
            for (int t = 0; t < 2; ++t) {
                int m = wm + t * 16 + m16;
                int cp = (ks * 4 + quad) ^ (m & 7);
                af[t] = *(const bf16x8*)&As[(m * 8 + cp) * 8];
                int n = wn + t * 16 + m16;
                int cq = (ks * 4 + quad) ^ (n & 7);
                bfv[t] = *(const bf16x8*)&Bs[(n * 8 + cq) * 8];
            }
            #pragma unroll
            for (int i = 0; i < 2; ++i)
                #pragma unroll
                for (int j = 0; j < 2; ++j)
                    acc[i][j] = __builtin_amdgcn_mfma_f32_16x16x32_bf16(
                        af[i], bfv[j], acc[i][j], 0, 0, 0);
        }
        __syncthreads();
    }

    #pragma unroll
    for (int i = 0; i < 2; ++i) {
        #pragma unroll
        for (int j = 0; j < 2; ++j) {
            int col = n0 + wn + j * 16 + m16;
            int rbase = r0 + wm + i * 16 + quad * 4;
            #pragma unroll
            for (int g = 0; g < 4; ++g)
                Cout[(size_t)(rbase + g) * 256 + col] = acc[i][j][g];
        }
    }
}

// ---------------------------------------------------------------------------
// MFMA GEMM (fc1): h1 = relu(diff @ fc1_wp^T + b). 32x64 tile, BK=64.
// ---------------------------------------------------------------------------
__global__ __launch_bounds__(256, 4) void fc1_gemm_kernel(
    const __hip_bfloat16* __restrict__ A,    // diff (1024 x 2304)
    const __hip_bfloat16* __restrict__ Bm,   // fc1_wp (1024 x 2304)
    const float* __restrict__ bias,
    float* __restrict__ C)                   // h1 (1024 x 1024)
{
    const int tid = threadIdx.x;
    const int wave = tid >> 6, lane = tid & 63;
    const int r0 = blockIdx.y * 32, n0 = blockIdx.x * 64;
    const int wm = (wave >> 1) * 16, wn = (wave & 1) * 32;
    const int m16 = lane & 15, quad = lane >> 4;
    const int K = FEATD_;
    __shared__ __align__(16) __hip_bfloat16 As[32 * 64];
    __shared__ __align__(16) __hip_bfloat16 Bs[64 * 64];

    f32x4 acc[2];
    acc[0] = (f32x4){0.f, 0.f, 0.f, 0.f};
    acc[1] = (f32x4){0.f, 0.f, 0.f, 0.f};

    const int qa = wave * 64 + lane;                 // 0..255
    const int msA = qa >> 3, csA = (qa & 7) ^ (msA & 7);
    const int qb1 = qa + 256;
    const int msB1 = qb1 >> 3, csB1 = (qb1 & 7) ^ (msB1 & 7);
    const size_t rA  = (size_t)(r0 + msA)  * K + csA  * 8;
    const size_t rB0 = (size_t)(n0 + msA)  * K + csA  * 8;
    const size_t rB1 = (size_t)(n0 + msB1) * K + csB1 * 8;

    for (int k0 = 0; k0 < K; k0 += 64) {
        gld16(A  + rA  + k0, &As[wave * 512]);
        gld16(Bm + rB0 + k0, &Bs[wave * 512]);
        gld16(Bm + rB1 + k0, &Bs[2048 + wave * 512]);
        __syncthreads();
        #pragma unroll
        for (int ks = 0; ks < 2; ++ks) {
            bf16x8 af, bfv[2];
            int m = wm + m16;
            int cp = (ks * 4 + quad) ^ (m & 7);
            af = *(const bf16x8*)&As[(m * 8 + cp) * 8];
            #pragma unroll
            for (int t = 0; t < 2; ++t) {
                int n = wn + t * 16 + m16;
                int cq = (ks * 4 + quad) ^ (n & 7);
                bfv[t] = *(const bf16x8*)&Bs[(n * 8 + cq) * 8];
            }
            #pragma unroll
            for (int j = 0; j < 2; ++j)
                acc[j] = __builtin_amdgcn_mfma_f32_16x16x32_bf16(
                    af, bfv[j], acc[j], 0, 0, 0);
        }
        __syncthreads();
    }

    #pragma unroll
    for (int j = 0; j < 2; ++j) {
        int col = n0 + wn + j * 16 + m16;
        int rbase = r0 + wm + quad * 4;
        float bv = bias[col];
        #pragma unroll
        for (int g = 0; g < 4; ++g) {
            int r = rbase + g;
            float v = acc[j][g] + bv;
            C[(size_t)r * H1_ + col] = v > 0.f ? v : 0.f;
        }
    }
}

// ---------------------------------------------------------------------------
// fc1_w (1024 x 2304 fp32, k = o*9+hw) -> bf16 permuted (k' = hw*256+o)
// ---------------------------------------------------------------------------
__global__ __launch_bounds__(256) void fc1w_perm_kernel(
    const float* __restrict__ src, __hip_bfloat16* __restrict__ dst)
{
    int h = blockIdx.x;
    int tid = threadIdx.x;
    __shared__ float buf[FEATD_];
    const float* s = src + (size_t)h * FEATD_;
    #pragma unroll
    for (int it = 0; it < 9; ++it)
        buf[it * 256 + tid] = s[it * 256 + tid];
    __syncthreads();
    __hip_bfloat16* d = dst + (size_t)h * FEATD_;
    #pragma unroll
    for (int it = 0; it < 9; ++it) {
        int dd = it * 256 + tid;       // hw = it, o = tid
        d[dd] = __float2bfloat16(buf[tid * HWC_ + it]);
    }
}

// ---------------------------------------------------------------------------
// inv[b][p] = n with pids[b][n]==p else -1
// ---------------------------------------------------------------------------
__global__ __launch_bounds__(64) void invmap_kernel(
    const int* __restrict__ pids, int* __restrict__ inv)
{
    int b = blockIdx.x;
    int p = threadIdx.x;
    if (p < P_) {
        int v = -1;
        for (int n = 0; n < N_; ++n)
            if (pids[b * N_ + n] == p) v = n;
        inv[b * P_ + p] = v;
    }
}

// ---------------------------------------------------------------------------
// meandiff (FUSED meanb+diff): mean kept in registers, feat re-read (L2-hot)
// ---------------------------------------------------------------------------
__global__ __launch_bounds__(256) void meandiff_kernel(
    const float* __restrict__ feat, const int* __restrict__ inv,
    __hip_bfloat16* __restrict__ diff)
{
    int p = blockIdx.x;
    int d = blockIdx.y * 256 + threadIdx.x;
    float acc = 0.0f;
    #pragma unroll 4
    for (int b = 0; b < B_; ++b) {
        int n = inv[b * P_ + p];
        if (n >= 0) acc += feat[(size_t)(b * N_ + n) * FEATD_ + d];
    }
    float mean = acc * (1.0f / (float)B_);
    #pragma unroll 4
    for (int b = 0; b < B_; ++b) {
        int n = inv[b * P_ + p];
        if (n >= 0) {
            size_t r = (size_t)(b * N_ + n);
            diff[r * FEATD_ + d] = __float2bfloat16(mean - feat[r * FEATD_ + d]);
        }
    }
}

// ---------------------------------------------------------------------------
// fc2: out[bn][o] = h1[bn] . fc2_w[o] + fc2_b[o]
// ---------------------------------------------------------------------------
__global__ __launch_bounds__(256) void fc2_kernel(
    const float* __restrict__ h1, const float* __restrict__ fc2_w,
    const float* __restrict__ fc2_b, float* __restrict__ out)
{
    int bn = blockIdx.x;
    int tid = threadIdx.x;
    __shared__ __align__(16) float row[H1_];
    __shared__ float partial[32][8];
    ((float4*)row)[tid] = ((const float4*)(h1 + (size_t)bn * H1_))[tid];
    __syncthreads();
    int o = tid >> 3, part = tid & 7;
    float acc = 0.0f;
    if (o < O_) {
        const float* wrow = fc2_w + (size_t)o * H1_ + part * 128;
        const float* hrow = row + part * 128;
        #pragma unroll 4
        for (int j = 0; j < 128; ++j) acc += hrow[j] * wrow[j];
    }
    partial[o][part] = acc;
    __syncthreads();
    if (part == 0 && o < O_) {
        float s = fc2_b[o];
        #pragma unroll
        for (int p = 0; p < 8; ++p) s += partial[o][p];
        out[(size_t)bn * O_ + o] = s;
    }
}

// ---------------------------------------------------------------------------
// Launch
// ---------------------------------------------------------------------------
extern "C" void kernel_launch(void* const* d_in, const int* in_sizes, int n_in,
                              void* d_out, int out_size, void* d_ws, size_t ws_size,
                              hipStream_t stream) {
    const float* fmap  = (const float*)d_in[0];
    const float* boxes = (const float*)d_in[1];
    const int*   pids  = (const int*)  d_in[2];
    const float* w1    = (const float*)d_in[3];
    const float* w2    = (const float*)d_in[4];
    const float* fc1_w = (const float*)d_in[5];
    const float* fc1_b = (const float*)d_in[6];
    const float* fc2_w = (const float*)d_in[7];
    const float* fc2_b = (const float*)d_in[8];
    float* out = (float*)d_out;

    // workspace layout (all 16B aligned; mean_b slot retained but unused)
    char* wsb = (char*)d_ws;
    __hip_bfloat16* Wc     = (__hip_bfloat16*)wsb;                      // 256*1024
    __hip_bfloat16* pooled = Wc + 256 * 1024;                           // 9216*1024
    __hip_bfloat16* fc1wp  = pooled + (size_t)PROWS_ * C_;              // 1024*2304
    __hip_bfloat16* diffp  = fc1wp + (size_t)H1_ * FEATD_;              // 1024*2304
    float* feat   = (float*)(diffp + (size_t)H1_ * FEATD_);             // 1024*2304
    float* mean_b = feat + (size_t)(B_ * N_) * FEATD_;                  // 20*2304 (unused)
    float* h1     = mean_b + (size_t)P_ * FEATD_;                       // 1024*1024
    int*   inv    = (int*)(h1 + (size_t)(B_ * N_) * H1_);               // 128*20
    float* wpart  = (float*)(inv + 128 * P_ + 64);                      // 8*256*1024

    hipLaunchKernelGGL(wcombine_split_kernel, dim3(16, 4, 8), dim3(256), 0, stream,
                       w1, w2, wpart);
    hipLaunchKernelGGL(wc_reduce_kernel, dim3(1024), dim3(256), 0, stream,
                       wpart, Wc);
    hipLaunchKernelGGL(roipool_kernel, dim3(C_ / CCH_, 128), dim3(256), 0, stream,
                       fmap, boxes, pooled);
    hipLaunchKernelGGL(pooledgemm_kernel, dim3(4, 144), dim3(256), 0, stream,
                       pooled, Wc, feat);
    hipLaunchKernelGGL(fc1w_perm_kernel, dim3(1024), dim3(256), 0, stream,
                       fc1_w, fc1wp);
    hipLaunchKernelGGL(invmap_kernel, dim3(128), dim3(64), 0, stream,
                       pids, inv);
    hipLaunchKernelGGL(meandiff_kernel, dim3(20, 9), dim3(256), 0, stream,
                       feat, inv, diffp);
    hipLaunchKernelGGL(fc1_gemm_kernel, dim3(16, 32), dim3(256), 0, stream,
                       diffp, fc1wp, fc1_b, h1);
    hipLaunchKernelGGL(fc2_kernel, dim3(1024), dim3(256), 0, stream,
                       h1, fc2_w, fc2_b, out);
}